// Round 11
// baseline (160.493 us; speedup 1.0000x reference)
//
#include <hip/hip_runtime.h>
#include <hip/hip_bf16.h>

#define CC 128

typedef __attribute__((ext_vector_type(8))) short short8;
typedef __attribute__((ext_vector_type(16))) float f32x16;

union I4S8 { int4 i; short8 s; int2 h[2]; };

__device__ __forceinline__ unsigned short f2bfu(float f) {
  union { float f; unsigned int i; } x; x.f = f;
  unsigned int r = x.i + 0x7fffu + ((x.i >> 16) & 1u);
  return (unsigned short)(r >> 16);
}
__device__ __forceinline__ short f2bfs(float f) { return (short)f2bfu(f); }
// packed f32x2 -> bf16x2 via compiler intrinsic (RNE, emits v_cvt_pk_bf16_f32)
__device__ __forceinline__ unsigned int pk2(float a, float b) {
  union { __hip_bfloat162 h; unsigned int u; } c;
  c.h = __float22bfloat162_rn(make_float2(a, b));
  return c.u;
}
__device__ __forceinline__ float bflo(unsigned int u) {
  union { unsigned int i; float f; } x; x.i = u << 16; return x.f;
}
__device__ __forceinline__ float bfhi(unsigned int u) {
  union { unsigned int i; float f; } x; x.i = u & 0xffff0000u; return x.f;
}
__device__ __forceinline__ float exp2_raw(float x) {
#if __has_builtin(__builtin_amdgcn_exp2f)
  return __builtin_amdgcn_exp2f(x);
#else
  return exp2f(x);
#endif
}
__device__ __forceinline__ f32x16 fzero16() {
  f32x16 z;
#pragma unroll
  for (int i = 0; i < 16; ++i) z[i] = 0.f;
  return z;
}
__device__ __forceinline__ void ld16(const float* p, float* f) {
#pragma unroll
  for (int i = 0; i < 4; ++i) {
    float4 a = *(const float4*)(p + 4 * i);
    f[4*i] = a.x; f[4*i+1] = a.y; f[4*i+2] = a.z; f[4*i+3] = a.w;
  }
}

// 1/sqrt(16) * log2(e): folded into Q so attention works in log2 domain
#define QSC 0.3606737602f
// V^T tile: [17 rows (d, +ones)][32 keys] shorts
#define VTILE 544

// ---------------- W: fp32 -> bf16 weight conversion ----------------
__global__ __launch_bounds__(256) void k_cvtw(
    const float* __restrict__ wil, const float* __restrict__ wol,
    const float* __restrict__ wis, const float* __restrict__ wos,
    short* __restrict__ o) {
  const int idx = (blockIdx.x * 256 + threadIdx.x) * 8;
  const float* src; int off;
  if (idx < 49152)       { src = wil; off = idx; }
  else if (idx < 65536)  { src = wol; off = idx - 49152; }
  else if (idx < 114688) { src = wis; off = idx - 65536; }
  else                   { src = wos; off = idx - 114688; }
  float f[8];
  float4 a = *(const float4*)(src + off), b = *(const float4*)(src + off + 4);
  f[0]=a.x; f[1]=a.y; f[2]=a.z; f[3]=a.w; f[4]=b.x; f[5]=b.y; f[6]=b.z; f[7]=b.w;
  short8 r;
#pragma unroll
  for (int j = 0; j < 8; ++j) r[j] = f2bfs(f[j]);
  *(short8*)(o + idx) = r;
}

// ---------------- K1: long QKV projection, MFMA ----------------
// Emits bf16 Q/K [pair=b*8+hh][l][d], tiled V^T vt[pair][kt=l>>5][17][32]
// (row 16 = bf16 ones), and pos_ct[c][tok] bf16.
__global__ __launch_bounds__(256) void k_proj_long(
    const float* __restrict__ q, const float* __restrict__ k,
    const float* __restrict__ v, const float* __restrict__ pq,
    const float* __restrict__ pk,
    const short* __restrict__ wbf, const float* __restrict__ b_in,
    short* __restrict__ qb, short* __restrict__ kb, short* __restrict__ vt,
    short* __restrict__ pos_ct) {
  __shared__ short XQ[32][132], XK[32][132], XV[32][132];
  const int tid = threadIdx.x;
  const int wid = tid >> 6, lane = tid & 63;
  const int l31 = lane & 31, g = lane >> 5;
  const int tok0 = blockIdx.x * 32;
  const int l = tok0 >> 9, b0 = tok0 & 511;
  const int t = l >> 4, bh = (l >> 2) & 3, bw = l & 3;
  const int nb = b0 >> 8, ph0 = (b0 >> 4) & 15;
  {
    const int c = tid >> 1, half = tid & 1;
    const int h = bh * 16 + ph0 + half, w0 = bw * 16;
    const size_t gb = (((size_t)(nb * CC + c) * 4 + t) << 12) + h * 64 + w0;
    float a[16], p[16];
    ld16(q + gb, a); ld16(pq + gb, p);
    {
      short8 s0, s1;
#pragma unroll
      for (int j = 0; j < 8; ++j) { s0[j] = f2bfs(p[j]); s1[j] = f2bfs(p[8 + j]); }
      short* pd = pos_ct + (size_t)c * 32768 + tok0 + half * 16;
      *(short8*)pd = s0;
      *(short8*)(pd + 8) = s1;
    }
#pragma unroll
    for (int j = 0; j < 16; ++j) XQ[half * 16 + j][c] = f2bfs(a[j] + p[j]);
    ld16(k + gb, a); ld16(pk + gb, p);
#pragma unroll
    for (int j = 0; j < 16; ++j) XK[half * 16 + j][c] = f2bfs(a[j] + p[j]);
    ld16(v + gb, a);
#pragma unroll
    for (int j = 0; j < 16; ++j) XV[half * 16 + j][c] = f2bfs(a[j]);
  }
  __syncthreads();
  for (int i = 0; i < 3; ++i) {
    const int nt = wid + 4 * i;
    const int nch = nt * 32 + l31;
    const int which = nt >> 2;
    const short (*X)[132] = (which == 0) ? XQ : (which == 1) ? XK : XV;
    f32x16 acc = fzero16();
#pragma unroll
    for (int k0 = 0; k0 < 128; k0 += 16) {
      I4S8 af;
      af.h[0] = *(const int2*)&X[l31][k0 + 8 * g];
      af.h[1] = *(const int2*)&X[l31][k0 + 8 * g + 4];
      short8 bf = *(const short8*)(wbf + nch * CC + k0 + 8 * g);
      acc = __builtin_amdgcn_mfma_f32_32x32x16_bf16(af.s, bf, acc, 0, 0, 0);
    }
    const float bias = b_in[nch];
    const int hh = (nch >> 4) & 7, d = nch & 15;
    if (which == 2) {
      const int kt = l >> 5, col = l & 31;
#pragma unroll
      for (int r = 0; r < 16; ++r) {
        const int tt = (r & 3) + 8 * (r >> 2) + 4 * g;
        const size_t pb_ = ((size_t)((b0 + tt) * 8 + hh) * 2 + kt) * VTILE;
        vt[pb_ + d * 32 + col] = f2bfs(acc[r] + bias);
        if (d == 0) vt[pb_ + 16 * 32 + col] = (short)0x3F80;  // ones row
      }
    } else {
      short* dst = (which == 0) ? qb : kb;
      const float sc = (which == 0) ? QSC : 1.0f;
#pragma unroll
      for (int r = 0; r < 16; ++r) {
        const int tt = (r & 3) + 8 * (r >> 2) + 4 * g;
        dst[((size_t)((b0 + tt) * 8 + hh) * 64 + l) * 16 + d] =
            f2bfs((acc[r] + bias) * sc);
      }
    }
  }
}

// ---------------- K2: unified MFMA flash attention (no LDS) ----------------
// S^T = mfma(K,Q) (Q pre-scaled by log2e/sqrt(d)); p = exp2(s) raw.
// PV A-operand read directly from tiled global V^T vt[pair][kt][17][32]
// (1088B hot block per tile); row 16 = ones -> acc[8] = lsum.
template<int SEQ, int BATCH>
__global__ __launch_bounds__(256) void k_attn(
    const short* __restrict__ qsp, const short* __restrict__ ksp,
    const short* __restrict__ vt, short* __restrict__ ao) {
  const int tid = threadIdx.x;
  const int wid = tid >> 6, lane = tid & 63;
  const int l31 = lane & 31, g = lane >> 5;
  const int WPP = SEQ / 32, NT = SEQ / 32;
  // XCD-chunk swizzle (bijective for 2048 = 8*256 blocks)
  const int blk = ((blockIdx.x & 7) << 8) | (blockIdx.x >> 3);
  const int gw = blk * 4 + wid;
  const int pair = gw / WPP;
  const int q0 = (gw % WPP) * 32;
  const int batch = pair >> 3, hh = pair & 7;
  const size_t pbase = (size_t)pair * (SEQ * 16);
  const int arow = (l31 < 16) ? l31 : 16;   // lanes 16..31 -> ones row (lsum)
  const short* vtp = vt + (size_t)pair * (NT * VTILE) + arow * 32;

  const short8 qf = *(const short8*)(qsp + pbase + (size_t)(q0 + l31) * 16 + 8 * g);

  f32x16 acc = fzero16();

#pragma unroll 2
  for (int kt = 0; kt < NT; ++kt) {
    const short8 kf =
        *(const short8*)(ksp + pbase + (size_t)(kt * 32 + l31) * 16 + 8 * g);
    f32x16 s = __builtin_amdgcn_mfma_f32_32x32x16_bf16(kf, qf, fzero16(), 0, 0, 0);

    I4S8 pa, pb;
#pragma unroll
    for (int j = 0; j < 4; ++j) {
      pa.i[j] = (int)pk2(exp2_raw(s[2 * j]), exp2_raw(s[2 * j + 1]));
      pb.i[j] = (int)pk2(exp2_raw(s[8 + 2 * j]), exp2_raw(s[9 + 2 * j]));
    }

    const short* vtt = vtp + kt * VTILE;
    I4S8 a1, a2;
    a1.h[0] = *(const int2*)(vtt + 4 * g);
    a1.h[1] = *(const int2*)(vtt + 8 + 4 * g);
    a2.h[0] = *(const int2*)(vtt + 16 + 4 * g);
    a2.h[1] = *(const int2*)(vtt + 24 + 4 * g);
    acc = __builtin_amdgcn_mfma_f32_32x32x16_bf16(a1.s, pa.s, acc, 0, 0, 0);
    acc = __builtin_amdgcn_mfma_f32_32x32x16_bf16(a2.s, pb.s, acc, 0, 0, 0);
  }

  const float inv = 1.0f / acc[8];   // ones-row accumulation = full lsum
  const int qi = q0 + l31;
  short* dst = ao + ((size_t)qi * BATCH + batch) * CC + hh * 16 + 4 * g;
  uint2 o1, o2;
  o1.x = pk2(acc[0] * inv, acc[1] * inv);
  o1.y = pk2(acc[2] * inv, acc[3] * inv);
  o2.x = pk2(acc[4] * inv, acc[5] * inv);
  o2.y = pk2(acc[6] * inv, acc[7] * inv);
  *(uint2*)dst = o1;
  *(uint2*)(dst + 8) = o2;
}

// ---------------- K3: long out-proj + pos + short QKV proj (MFMA x2) ----------------
__global__ __launch_bounds__(256) void k_mid(
    const short* __restrict__ ao, const short* __restrict__ pos_ct,
    const short* __restrict__ wobf, const float* __restrict__ b_out_l,
    const short* __restrict__ wibf, const float* __restrict__ b_in_s,
    short* __restrict__ qb, short* __restrict__ kb, short* __restrict__ vt) {
  __shared__ short YQK[32][132], YV[32][132];
  const int tid = threadIdx.x;
  const int wid = tid >> 6, lane = tid & 63;
  const int l31 = lane & 31, g = lane >> 5;
  const int tok0 = blockIdx.x * 32;
  const int l = tok0 >> 9, b0 = tok0 & 511;
  const int t = l >> 4, bh = (l >> 2) & 3, bw = l & 3;
  const int nb = b0 >> 8, ph0 = (b0 >> 4) & 15;
  {
    const int nch = wid * 32 + l31;
    f32x16 acc = fzero16();
#pragma unroll
    for (int k0 = 0; k0 < 128; k0 += 16) {
      short8 af = *(const short8*)(ao + (size_t)(tok0 + l31) * CC + k0 + 8 * g);
      short8 bf = *(const short8*)(wobf + nch * CC + k0 + 8 * g);
      acc = __builtin_amdgcn_mfma_f32_32x32x16_bf16(af, bf, acc, 0, 0, 0);
    }
    const float bias = b_out_l[nch];
    float pos[16];
#pragma unroll
    for (int rr = 0; rr < 4; ++rr) {
      int2 pp = *(const int2*)(pos_ct + (size_t)nch * 32768 + tok0 + rr * 8 + 4 * g);
      pos[rr * 4 + 0] = bflo((unsigned int)pp.x);
      pos[rr * 4 + 1] = bfhi((unsigned int)pp.x);
      pos[rr * 4 + 2] = bflo((unsigned int)pp.y);
      pos[rr * 4 + 3] = bfhi((unsigned int)pp.y);
    }
#pragma unroll
    for (int r = 0; r < 16; ++r) {
      const int tt = (r & 3) + 8 * (r >> 2) + 4 * g;
      const float y = acc[r] + bias;
      YV[tt][nch] = f2bfs(y);
      YQK[tt][nch] = f2bfs(y + pos[r]);
    }
  }
  __syncthreads();
  const int bs = nb * 16 + bh * 4 + bw;
  const int ls0 = (t * 16 + ph0) * 16;      // multiple of 32
  for (int i = 0; i < 3; ++i) {
    const int nt = wid + 4 * i;
    const int nch = nt * 32 + l31;
    const int which = nt >> 2;
    const short (*X)[132] = (which == 2) ? YV : YQK;
    f32x16 acc = fzero16();
#pragma unroll
    for (int k0 = 0; k0 < 128; k0 += 16) {
      I4S8 af;
      af.h[0] = *(const int2*)&X[l31][k0 + 8 * g];
      af.h[1] = *(const int2*)&X[l31][k0 + 8 * g + 4];
      short8 bf = *(const short8*)(wibf + nch * CC + k0 + 8 * g);
      acc = __builtin_amdgcn_mfma_f32_32x32x16_bf16(af.s, bf, acc, 0, 0, 0);
    }
    const float bias = b_in_s[nch];
    const int hh = (nch >> 4) & 7, d = nch & 15;
    if (which == 2) {
      const int kt = ls0 >> 5;
      const size_t base2 = ((size_t)(bs * 8 + hh) * 32 + kt) * VTILE;
#pragma unroll
      for (int rr = 0; rr < 4; ++rr) {
        const int c0 = rr * 8 + 4 * g;      // key columns c0..c0+3
        uint2 wv;
        wv.x = pk2(acc[rr * 4 + 0] + bias, acc[rr * 4 + 1] + bias);
        wv.y = pk2(acc[rr * 4 + 2] + bias, acc[rr * 4 + 3] + bias);
        *(uint2*)(vt + base2 + d * 32 + c0) = wv;
        if (d == 0) {
          uint2 on; on.x = 0x3F803F80u; on.y = 0x3F803F80u;
          *(uint2*)(vt + base2 + 16 * 32 + c0) = on;
        }
      }
    } else {
      short* dst = (which == 0) ? qb : kb;
      const float sc = (which == 0) ? QSC : 1.0f;
      const size_t base = ((size_t)(bs * 8 + hh) * 1024 + ls0) * 16 + d;
#pragma unroll
      for (int r = 0; r < 16; ++r) {
        const int tt = (r & 3) + 8 * (r >> 2) + 4 * g;
        dst[base + (size_t)tt * 16] = f2bfs((acc[r] + bias) * sc);
      }
    }
  }
}

// ---------------- K4: short out-proj + scatter to (N,C,T,H,W) fp32, MFMA ----------------
__global__ __launch_bounds__(256) void k_out_short(
    const short* __restrict__ ao, const short* __restrict__ wbf,
    const float* __restrict__ b_out, float* __restrict__ out) {
  const int tid = threadIdx.x;
  const int wid = tid >> 6, lane = tid & 63;
  const int l31 = lane & 31, g = lane >> 5;
  const int bs = blockIdx.x & 31;
  const int qi0 = (blockIdx.x >> 5) << 5;
  const int nb = bs >> 4, bh = (bs >> 2) & 3, bw = bs & 3;
  const int t = qi0 >> 8, ph0 = (qi0 >> 4) & 15;
  const int nch = wid * 32 + l31;
  f32x16 acc = fzero16();
#pragma unroll
  for (int k0 = 0; k0 < 128; k0 += 16) {
    short8 af = *(const short8*)(ao + ((size_t)(qi0 + l31) * 32 + bs) * CC + k0 + 8 * g);
    short8 bf = *(const short8*)(wbf + nch * CC + k0 + 8 * g);
    acc = __builtin_amdgcn_mfma_f32_32x32x16_bf16(af, bf, acc, 0, 0, 0);
  }
  const float bias = b_out[nch];
#pragma unroll
  for (int rr = 0; rr < 4; ++rr) {
    const int tt0 = rr * 8 + 4 * g;
    const int ph_off = tt0 >> 4, pw = tt0 & 15;
    const int h = bh * 16 + ph0 + ph_off, w = bw * 16 + pw;
    const size_t adr = (((size_t)(nb * CC + nch) * 4 + t) << 12) + h * 64 + w;
    float4 f;
    f.x = acc[rr * 4 + 0] + bias; f.y = acc[rr * 4 + 1] + bias;
    f.z = acc[rr * 4 + 2] + bias; f.w = acc[rr * 4 + 3] + bias;
    *(float4*)(out + adr) = f;
  }
}

extern "C" void kernel_launch(void* const* d_in, const int* in_sizes, int n_in,
                              void* d_out, int out_size, void* d_ws, size_t ws_size,
                              hipStream_t stream) {
  (void)in_sizes; (void)n_in; (void)out_size; (void)ws_size;
  const float* q   = (const float*)d_in[0];
  const float* k   = (const float*)d_in[1];
  const float* v   = (const float*)d_in[2];
  const float* pq  = (const float*)d_in[3];
  const float* pk  = (const float*)d_in[4];
  const float* wil = (const float*)d_in[5];
  const float* bil = (const float*)d_in[6];
  const float* wol = (const float*)d_in[7];
  const float* bol = (const float*)d_in[8];
  const float* wis = (const float*)d_in[9];
  const float* bis = (const float*)d_in[10];
  const float* wos = (const float*)d_in[11];
  const float* bos = (const float*)d_in[12];

  short* qs     = (short*)d_ws;            // 4.19M shorts each region
  short* ksb    = qs + 4194304;
  short* ao     = ksb + 4194304;
  short* pos_ct = ao + 4194304;
  short* wbf    = pos_ct + 4194304;        // 131072 shorts
  short* vt     = wbf + 131072;            // 4.46M shorts: tiled V^T + ones

  k_cvtw<<<dim3(64), dim3(256), 0, stream>>>(wil, wol, wis, wos, wbf);
  k_proj_long<<<dim3(1024), dim3(256), 0, stream>>>(q, k, v, pq, pk, wbf, bil,
                                                    qs, ksb, vt, pos_ct);
  k_attn<64, 512><<<dim3(2048), dim3(256), 0, stream>>>(qs, ksb, vt, ao);
  k_mid<<<dim3(1024), dim3(256), 0, stream>>>(ao, pos_ct, wbf + 49152, bol,
                                              wbf + 65536, bis, qs, ksb, vt);
  k_attn<1024, 32><<<dim3(2048), dim3(256), 0, stream>>>(qs, ksb, vt, ao);
  k_out_short<<<dim3(1024), dim3(256), 0, stream>>>(ao, wbf + 114688, bos,
                                                    (float*)d_out);
}

// Round 12
// 145.704 us; speedup vs baseline: 1.1015x; 1.1015x over previous
//
#include <hip/hip_runtime.h>
#include <hip/hip_bf16.h>

#define CC 128

typedef __attribute__((ext_vector_type(8))) short short8;
typedef __attribute__((ext_vector_type(16))) float f32x16;

union I4S8 { int4 i; short8 s; int2 h[2]; };

__device__ __forceinline__ unsigned short f2bfu(float f) {
  union { float f; unsigned int i; } x; x.f = f;
  unsigned int r = x.i + 0x7fffu + ((x.i >> 16) & 1u);
  return (unsigned short)(r >> 16);
}
__device__ __forceinline__ short f2bfs(float f) { return (short)f2bfu(f); }
// packed f32x2 -> bf16x2 via compiler intrinsic (RNE, emits v_cvt_pk_bf16_f32)
__device__ __forceinline__ unsigned int pk2(float a, float b) {
  union { __hip_bfloat162 h; unsigned int u; } c;
  c.h = __float22bfloat162_rn(make_float2(a, b));
  return c.u;
}
__device__ __forceinline__ float bflo(unsigned int u) {
  union { unsigned int i; float f; } x; x.i = u << 16; return x.f;
}
__device__ __forceinline__ float bfhi(unsigned int u) {
  union { unsigned int i; float f; } x; x.i = u & 0xffff0000u; return x.f;
}
// guaranteed single-instruction 2^x (v_exp_f32); asm fallback is 1-src/1-dst,
// no operand-packing ambiguity (r6 lesson applied narrowly)
__device__ __forceinline__ float exp2_raw(float x) {
#if __has_builtin(__builtin_amdgcn_exp2f)
  return __builtin_amdgcn_exp2f(x);
#else
  float r; asm("v_exp_f32 %0, %1" : "=v"(r) : "v"(x)); return r;
#endif
}
__device__ __forceinline__ f32x16 fzero16() {
  f32x16 z;
#pragma unroll
  for (int i = 0; i < 16; ++i) z[i] = 0.f;
  return z;
}
__device__ __forceinline__ void ld16(const float* p, float* f) {
#pragma unroll
  for (int i = 0; i < 4; ++i) {
    float4 a = *(const float4*)(p + 4 * i);
    f[4*i] = a.x; f[4*i+1] = a.y; f[4*i+2] = a.z; f[4*i+3] = a.w;
  }
}

// 1/sqrt(16) * log2(e): folded into Q so attention works in log2 domain
#define QSC 0.3606737602f

// ---------------- W: fp32 -> bf16 weight conversion ----------------
__global__ __launch_bounds__(256) void k_cvtw(
    const float* __restrict__ wil, const float* __restrict__ wol,
    const float* __restrict__ wis, const float* __restrict__ wos,
    short* __restrict__ o) {
  const int idx = (blockIdx.x * 256 + threadIdx.x) * 8;
  const float* src; int off;
  if (idx < 49152)       { src = wil; off = idx; }
  else if (idx < 65536)  { src = wol; off = idx - 49152; }
  else if (idx < 114688) { src = wis; off = idx - 65536; }
  else                   { src = wos; off = idx - 114688; }
  float f[8];
  float4 a = *(const float4*)(src + off), b = *(const float4*)(src + off + 4);
  f[0]=a.x; f[1]=a.y; f[2]=a.z; f[3]=a.w; f[4]=b.x; f[5]=b.y; f[6]=b.z; f[7]=b.w;
  short8 r;
#pragma unroll
  for (int j = 0; j < 8; ++j) r[j] = f2bfs(f[j]);
  *(short8*)(o + idx) = r;
}

// ---------------- K1: long QKV projection, MFMA ----------------
// Emits bf16 Q/K/V [pair=b*8+hh][l][d] and pos_ct[c][tok] bf16.
__global__ __launch_bounds__(256) void k_proj_long(
    const float* __restrict__ q, const float* __restrict__ k,
    const float* __restrict__ v, const float* __restrict__ pq,
    const float* __restrict__ pk,
    const short* __restrict__ wbf, const float* __restrict__ b_in,
    short* __restrict__ qb, short* __restrict__ kb, short* __restrict__ vb,
    short* __restrict__ pos_ct) {
  __shared__ short XQ[32][132], XK[32][132], XV[32][132];
  const int tid = threadIdx.x;
  const int wid = tid >> 6, lane = tid & 63;
  const int l31 = lane & 31, g = lane >> 5;
  const int tok0 = blockIdx.x * 32;
  const int l = tok0 >> 9, b0 = tok0 & 511;
  const int t = l >> 4, bh = (l >> 2) & 3, bw = l & 3;
  const int nb = b0 >> 8, ph0 = (b0 >> 4) & 15;
  {
    const int c = tid >> 1, half = tid & 1;
    const int h = bh * 16 + ph0 + half, w0 = bw * 16;
    const size_t gb = (((size_t)(nb * CC + c) * 4 + t) << 12) + h * 64 + w0;
    float a[16], p[16];
    ld16(q + gb, a); ld16(pq + gb, p);
    {
      short8 s0, s1;
#pragma unroll
      for (int j = 0; j < 8; ++j) { s0[j] = f2bfs(p[j]); s1[j] = f2bfs(p[8 + j]); }
      short* pd = pos_ct + (size_t)c * 32768 + tok0 + half * 16;
      *(short8*)pd = s0;
      *(short8*)(pd + 8) = s1;
    }
#pragma unroll
    for (int j = 0; j < 16; ++j) XQ[half * 16 + j][c] = f2bfs(a[j] + p[j]);
    ld16(k + gb, a); ld16(pk + gb, p);
#pragma unroll
    for (int j = 0; j < 16; ++j) XK[half * 16 + j][c] = f2bfs(a[j] + p[j]);
    ld16(v + gb, a);
#pragma unroll
    for (int j = 0; j < 16; ++j) XV[half * 16 + j][c] = f2bfs(a[j]);
  }
  __syncthreads();
  for (int i = 0; i < 3; ++i) {
    const int nt = wid + 4 * i;
    const int nch = nt * 32 + l31;
    const int which = nt >> 2;
    const short (*X)[132] = (which == 0) ? XQ : (which == 1) ? XK : XV;
    f32x16 acc = fzero16();
#pragma unroll
    for (int k0 = 0; k0 < 128; k0 += 16) {
      I4S8 af;
      af.h[0] = *(const int2*)&X[l31][k0 + 8 * g];
      af.h[1] = *(const int2*)&X[l31][k0 + 8 * g + 4];
      short8 bf = *(const short8*)(wbf + nch * CC + k0 + 8 * g);
      acc = __builtin_amdgcn_mfma_f32_32x32x16_bf16(af.s, bf, acc, 0, 0, 0);
    }
    const float bias = b_in[nch];
    const int hh = (nch >> 4) & 7, d = nch & 15;
    short* dst = (which == 0) ? qb : (which == 1) ? kb : vb;
    const float sc = (which == 0) ? QSC : 1.0f;
#pragma unroll
    for (int r = 0; r < 16; ++r) {
      const int tt = (r & 3) + 8 * (r >> 2) + 4 * g;
      dst[((size_t)((b0 + tt) * 8 + hh) * 64 + l) * 16 + d] =
          f2bfs((acc[r] + bias) * sc);
    }
  }
}

// ---------------- K2: unified MFMA flash attention (Q64/wave, static-max exp2,
// MFMA lsum). S^T = mfma(K,Q); p = exp2(s) raw; per-wave V^T LDS tile [17][36]
// with ones row 16 -> acc[8] = lsum. K/V loads + staging + A-frag reads are
// shared across both 32-query groups.
template<int SEQ, int BATCH>
__global__ __launch_bounds__(256) void k_attn(
    const short* __restrict__ qsp, const short* __restrict__ ksp,
    const short* __restrict__ vsp, short* __restrict__ ao) {
  __shared__ short vt[4][17 * 36];
  const int tid = threadIdx.x;
  const int wid = tid >> 6, lane = tid & 63;
  const int l31 = lane & 31, g = lane >> 5;
  const int WPP = SEQ / 64;  // 64-query blocks per pair
  // XCD-chunk swizzle (bijective for 1024 = 8*128 blocks)
  const int blk = ((blockIdx.x & 7) << 7) | (blockIdx.x >> 3);
  const int gw = blk * 4 + wid;
  const int pair = gw / WPP;
  const int q0 = (gw % WPP) * 64;
  const int batch = pair >> 3, hh = pair & 7;
  const size_t pbase = (size_t)pair * (SEQ * 16);
  short* vtw = &vt[wid][0];
  // ones row (A rows 16..31): 18 lanes write one b32 each, once
  if (lane < 18) *(int*)(vtw + 16 * 36 + 2 * lane) = 0x3F803F80;

  const short8 qf0 = *(const short8*)(qsp + pbase + (size_t)(q0 + l31) * 16 + 8 * g);
  const short8 qf1 = *(const short8*)(qsp + pbase + (size_t)(q0 + 32 + l31) * 16 + 8 * g);

  f32x16 acc0 = fzero16(), acc1 = fzero16();
  const int arow = (l31 < 16) ? l31 : 16;
  const short* vtr = vtw + arow * 36;

  for (int k0 = 0; k0 < SEQ; k0 += 32) {
    const short8 kf = *(const short8*)(ksp + pbase + (size_t)(k0 + l31) * 16 + 8 * g);
    const short8 vf = *(const short8*)(vsp + pbase + (size_t)(k0 + l31) * 16 + 8 * g);
#pragma unroll
    for (int j = 0; j < 8; ++j)
      vtw[(8 * g + j) * 36 + l31] = vf[j];

    f32x16 s0 = __builtin_amdgcn_mfma_f32_32x32x16_bf16(kf, qf0, fzero16(), 0, 0, 0);
    f32x16 s1 = __builtin_amdgcn_mfma_f32_32x32x16_bf16(kf, qf1, fzero16(), 0, 0, 0);

    I4S8 pa0, pb0, pa1, pb1;
#pragma unroll
    for (int j = 0; j < 4; ++j) {
      pa0.i[j] = (int)pk2(exp2_raw(s0[2 * j]), exp2_raw(s0[2 * j + 1]));
      pb0.i[j] = (int)pk2(exp2_raw(s0[8 + 2 * j]), exp2_raw(s0[9 + 2 * j]));
    }
#pragma unroll
    for (int j = 0; j < 4; ++j) {
      pa1.i[j] = (int)pk2(exp2_raw(s1[2 * j]), exp2_raw(s1[2 * j + 1]));
      pb1.i[j] = (int)pk2(exp2_raw(s1[8 + 2 * j]), exp2_raw(s1[9 + 2 * j]));
    }

    I4S8 a1, a2;
    a1.h[0] = *(const int2*)(vtr + 4 * g);
    a1.h[1] = *(const int2*)(vtr + 8 + 4 * g);
    a2.h[0] = *(const int2*)(vtr + 16 + 4 * g);
    a2.h[1] = *(const int2*)(vtr + 24 + 4 * g);
    acc0 = __builtin_amdgcn_mfma_f32_32x32x16_bf16(a1.s, pa0.s, acc0, 0, 0, 0);
    acc0 = __builtin_amdgcn_mfma_f32_32x32x16_bf16(a2.s, pb0.s, acc0, 0, 0, 0);
    acc1 = __builtin_amdgcn_mfma_f32_32x32x16_bf16(a1.s, pa1.s, acc1, 0, 0, 0);
    acc1 = __builtin_amdgcn_mfma_f32_32x32x16_bf16(a2.s, pb1.s, acc1, 0, 0, 0);
  }

  const float inv0 = 1.0f / acc0[8];   // ones-row accumulation = full lsum
  const float inv1 = 1.0f / acc1[8];
  const int qi = q0 + l31;
  short* dst0 = ao + ((size_t)qi * BATCH + batch) * CC + hh * 16 + 4 * g;
  short* dst1 = ao + ((size_t)(qi + 32) * BATCH + batch) * CC + hh * 16 + 4 * g;
  uint2 o1, o2;
  o1.x = pk2(acc0[0] * inv0, acc0[1] * inv0);
  o1.y = pk2(acc0[2] * inv0, acc0[3] * inv0);
  o2.x = pk2(acc0[4] * inv0, acc0[5] * inv0);
  o2.y = pk2(acc0[6] * inv0, acc0[7] * inv0);
  *(uint2*)dst0 = o1;
  *(uint2*)(dst0 + 8) = o2;
  o1.x = pk2(acc1[0] * inv1, acc1[1] * inv1);
  o1.y = pk2(acc1[2] * inv1, acc1[3] * inv1);
  o2.x = pk2(acc1[4] * inv1, acc1[5] * inv1);
  o2.y = pk2(acc1[6] * inv1, acc1[7] * inv1);
  *(uint2*)dst1 = o1;
  *(uint2*)(dst1 + 8) = o2;
}

// ---------------- K3: long out-proj + pos + short QKV proj (MFMA x2) ----------------
__global__ __launch_bounds__(256) void k_mid(
    const short* __restrict__ ao, const short* __restrict__ pos_ct,
    const short* __restrict__ wobf, const float* __restrict__ b_out_l,
    const short* __restrict__ wibf, const float* __restrict__ b_in_s,
    short* __restrict__ qb, short* __restrict__ kb, short* __restrict__ vb) {
  __shared__ short YQK[32][132], YV[32][132];
  const int tid = threadIdx.x;
  const int wid = tid >> 6, lane = tid & 63;
  const int l31 = lane & 31, g = lane >> 5;
  const int tok0 = blockIdx.x * 32;
  const int l = tok0 >> 9, b0 = tok0 & 511;
  const int t = l >> 4, bh = (l >> 2) & 3, bw = l & 3;
  const int nb = b0 >> 8, ph0 = (b0 >> 4) & 15;
  {
    const int nch = wid * 32 + l31;
    f32x16 acc = fzero16();
#pragma unroll
    for (int k0 = 0; k0 < 128; k0 += 16) {
      short8 af = *(const short8*)(ao + (size_t)(tok0 + l31) * CC + k0 + 8 * g);
      short8 bf = *(const short8*)(wobf + nch * CC + k0 + 8 * g);
      acc = __builtin_amdgcn_mfma_f32_32x32x16_bf16(af, bf, acc, 0, 0, 0);
    }
    const float bias = b_out_l[nch];
    float pos[16];
#pragma unroll
    for (int rr = 0; rr < 4; ++rr) {
      int2 pp = *(const int2*)(pos_ct + (size_t)nch * 32768 + tok0 + rr * 8 + 4 * g);
      pos[rr * 4 + 0] = bflo((unsigned int)pp.x);
      pos[rr * 4 + 1] = bfhi((unsigned int)pp.x);
      pos[rr * 4 + 2] = bflo((unsigned int)pp.y);
      pos[rr * 4 + 3] = bfhi((unsigned int)pp.y);
    }
#pragma unroll
    for (int r = 0; r < 16; ++r) {
      const int tt = (r & 3) + 8 * (r >> 2) + 4 * g;
      const float y = acc[r] + bias;
      YV[tt][nch] = f2bfs(y);
      YQK[tt][nch] = f2bfs(y + pos[r]);
    }
  }
  __syncthreads();
  const int bs = nb * 16 + bh * 4 + bw;
  const int ls0 = (t * 16 + ph0) * 16;
  for (int i = 0; i < 3; ++i) {
    const int nt = wid + 4 * i;
    const int nch = nt * 32 + l31;
    const int which = nt >> 2;
    const short (*X)[132] = (which == 2) ? YV : YQK;
    f32x16 acc = fzero16();
#pragma unroll
    for (int k0 = 0; k0 < 128; k0 += 16) {
      I4S8 af;
      af.h[0] = *(const int2*)&X[l31][k0 + 8 * g];
      af.h[1] = *(const int2*)&X[l31][k0 + 8 * g + 4];
      short8 bf = *(const short8*)(wibf + nch * CC + k0 + 8 * g);
      acc = __builtin_amdgcn_mfma_f32_32x32x16_bf16(af.s, bf, acc, 0, 0, 0);
    }
    const float bias = b_in_s[nch];
    const int hh = (nch >> 4) & 7, d = nch & 15;
    short* dst = (which == 0) ? qb : (which == 1) ? kb : vb;
    const float sc = (which == 0) ? QSC : 1.0f;
    const size_t base = ((size_t)(bs * 8 + hh) * 1024 + ls0) * 16 + d;
#pragma unroll
    for (int r = 0; r < 16; ++r) {
      const int tt = (r & 3) + 8 * (r >> 2) + 4 * g;
      dst[base + (size_t)tt * 16] = f2bfs((acc[r] + bias) * sc);
    }
  }
}

// ---------------- K4: short out-proj + scatter to (N,C,T,H,W) fp32, MFMA ----------------
__global__ __launch_bounds__(256) void k_out_short(
    const short* __restrict__ ao, const short* __restrict__ wbf,
    const float* __restrict__ b_out, float* __restrict__ out) {
  const int tid = threadIdx.x;
  const int wid = tid >> 6, lane = tid & 63;
  const int l31 = lane & 31, g = lane >> 5;
  const int bs = blockIdx.x & 31;
  const int qi0 = (blockIdx.x >> 5) << 5;
  const int nb = bs >> 4, bh = (bs >> 2) & 3, bw = bs & 3;
  const int t = qi0 >> 8, ph0 = (qi0 >> 4) & 15;
  const int nch = wid * 32 + l31;
  f32x16 acc = fzero16();
#pragma unroll
  for (int k0 = 0; k0 < 128; k0 += 16) {
    short8 af = *(const short8*)(ao + ((size_t)(qi0 + l31) * 32 + bs) * CC + k0 + 8 * g);
    short8 bf = *(const short8*)(wbf + nch * CC + k0 + 8 * g);
    acc = __builtin_amdgcn_mfma_f32_32x32x16_bf16(af, bf, acc, 0, 0, 0);
  }
  const float bias = b_out[nch];
#pragma unroll
  for (int rr = 0; rr < 4; ++rr) {
    const int tt0 = rr * 8 + 4 * g;
    const int ph_off = tt0 >> 4, pw = tt0 & 15;
    const int h = bh * 16 + ph0 + ph_off, w = bw * 16 + pw;
    const size_t adr = (((size_t)(nb * CC + nch) * 4 + t) << 12) + h * 64 + w;
    float4 f;
    f.x = acc[rr * 4 + 0] + bias; f.y = acc[rr * 4 + 1] + bias;
    f.z = acc[rr * 4 + 2] + bias; f.w = acc[rr * 4 + 3] + bias;
    *(float4*)(out + adr) = f;
  }
}

extern "C" void kernel_launch(void* const* d_in, const int* in_sizes, int n_in,
                              void* d_out, int out_size, void* d_ws, size_t ws_size,
                              hipStream_t stream) {
  (void)in_sizes; (void)n_in; (void)out_size; (void)ws_size;
  const float* q   = (const float*)d_in[0];
  const float* k   = (const float*)d_in[1];
  const float* v   = (const float*)d_in[2];
  const float* pq  = (const float*)d_in[3];
  const float* pk  = (const float*)d_in[4];
  const float* wil = (const float*)d_in[5];
  const float* bil = (const float*)d_in[6];
  const float* wol = (const float*)d_in[7];
  const float* bol = (const float*)d_in[8];
  const float* wis = (const float*)d_in[9];
  const float* bis = (const float*)d_in[10];
  const float* wos = (const float*)d_in[11];
  const float* bos = (const float*)d_in[12];

  short* qs     = (short*)d_ws;            // 4.19M shorts each region
  short* ksb    = qs + 4194304;
  short* vsb    = ksb + 4194304;
  short* ao     = vsb + 4194304;
  short* pos_ct = ao + 4194304;
  short* wbf    = pos_ct + 4194304;        // 131072 shorts

  k_cvtw<<<dim3(64), dim3(256), 0, stream>>>(wil, wol, wis, wos, wbf);
  k_proj_long<<<dim3(1024), dim3(256), 0, stream>>>(q, k, v, pq, pk, wbf, bil,
                                                    qs, ksb, vsb, pos_ct);
  k_attn<64, 512><<<dim3(1024), dim3(256), 0, stream>>>(qs, ksb, vsb, ao);
  k_mid<<<dim3(1024), dim3(256), 0, stream>>>(ao, pos_ct, wbf + 49152, bol,
                                              wbf + 65536, bis, qs, ksb, vsb);
  k_attn<1024, 32><<<dim3(1024), dim3(256), 0, stream>>>(qs, ksb, vsb, ao);
  k_out_short<<<dim3(1024), dim3(256), 0, stream>>>(ao, wbf + 114688, bos,
                                                    (float*)d_out);
}

// Round 13
// 143.270 us; speedup vs baseline: 1.1202x; 1.0170x over previous
//
#include <hip/hip_runtime.h>
#include <hip/hip_bf16.h>

#define CC 128

typedef __attribute__((ext_vector_type(8))) short short8;
typedef __attribute__((ext_vector_type(16))) float f32x16;

union I4S8 { int4 i; short8 s; int2 h[2]; };

__device__ __forceinline__ unsigned short f2bfu(float f) {
  union { float f; unsigned int i; } x; x.f = f;
  unsigned int r = x.i + 0x7fffu + ((x.i >> 16) & 1u);
  return (unsigned short)(r >> 16);
}
__device__ __forceinline__ short f2bfs(float f) { return (short)f2bfu(f); }
// packed f32x2 -> bf16x2 via compiler intrinsic (RNE, emits v_cvt_pk_bf16_f32)
__device__ __forceinline__ unsigned int pk2(float a, float b) {
  union { __hip_bfloat162 h; unsigned int u; } c;
  c.h = __float22bfloat162_rn(make_float2(a, b));
  return c.u;
}
__device__ __forceinline__ float bflo(unsigned int u) {
  union { unsigned int i; float f; } x; x.i = u << 16; return x.f;
}
__device__ __forceinline__ float bfhi(unsigned int u) {
  union { unsigned int i; float f; } x; x.i = u & 0xffff0000u; return x.f;
}
// guaranteed single-instruction 2^x (v_exp_f32); 1-src/1-dst asm fallback
__device__ __forceinline__ float exp2_raw(float x) {
#if __has_builtin(__builtin_amdgcn_exp2f)
  return __builtin_amdgcn_exp2f(x);
#else
  float r; asm("v_exp_f32 %0, %1" : "=v"(r) : "v"(x)); return r;
#endif
}
__device__ __forceinline__ f32x16 fzero16() {
  f32x16 z;
#pragma unroll
  for (int i = 0; i < 16; ++i) z[i] = 0.f;
  return z;
}
__device__ __forceinline__ void ld16(const float* p, float* f) {
#pragma unroll
  for (int i = 0; i < 4; ++i) {
    float4 a = *(const float4*)(p + 4 * i);
    f[4*i] = a.x; f[4*i+1] = a.y; f[4*i+2] = a.z; f[4*i+3] = a.w;
  }
}

// 1/sqrt(16) * log2(e): folded into Q so attention works in log2 domain
#define QSC 0.3606737602f

// ---------------- W: fp32 -> bf16 weight conversion ----------------
__global__ __launch_bounds__(256) void k_cvtw(
    const float* __restrict__ wil, const float* __restrict__ wol,
    const float* __restrict__ wis, const float* __restrict__ wos,
    short* __restrict__ o) {
  const int idx = (blockIdx.x * 256 + threadIdx.x) * 8;
  const float* src; int off;
  if (idx < 49152)       { src = wil; off = idx; }
  else if (idx < 65536)  { src = wol; off = idx - 49152; }
  else if (idx < 114688) { src = wis; off = idx - 65536; }
  else                   { src = wos; off = idx - 114688; }
  float f[8];
  float4 a = *(const float4*)(src + off), b = *(const float4*)(src + off + 4);
  f[0]=a.x; f[1]=a.y; f[2]=a.z; f[3]=a.w; f[4]=b.x; f[5]=b.y; f[6]=b.z; f[7]=b.w;
  short8 r;
#pragma unroll
  for (int j = 0; j < 8; ++j) r[j] = f2bfs(f[j]);
  *(short8*)(o + idx) = r;
}

// ---------------- K1: long QKV projection, MFMA ----------------
// Emits bf16 Q/K/V [pair=b*8+hh][l][d] and pos_ct[c][tok] bf16.
__global__ __launch_bounds__(256) void k_proj_long(
    const float* __restrict__ q, const float* __restrict__ k,
    const float* __restrict__ v, const float* __restrict__ pq,
    const float* __restrict__ pk,
    const short* __restrict__ wbf, const float* __restrict__ b_in,
    short* __restrict__ qb, short* __restrict__ kb, short* __restrict__ vb,
    short* __restrict__ pos_ct) {
  __shared__ short XQ[32][132], XK[32][132], XV[32][132];
  const int tid = threadIdx.x;
  const int wid = tid >> 6, lane = tid & 63;
  const int l31 = lane & 31, g = lane >> 5;
  const int tok0 = blockIdx.x * 32;
  const int l = tok0 >> 9, b0 = tok0 & 511;
  const int t = l >> 4, bh = (l >> 2) & 3, bw = l & 3;
  const int nb = b0 >> 8, ph0 = (b0 >> 4) & 15;
  {
    const int c = tid >> 1, half = tid & 1;
    const int h = bh * 16 + ph0 + half, w0 = bw * 16;
    const size_t gb = (((size_t)(nb * CC + c) * 4 + t) << 12) + h * 64 + w0;
    float a[16], p[16];
    ld16(q + gb, a); ld16(pq + gb, p);
    {
      short8 s0, s1;
#pragma unroll
      for (int j = 0; j < 8; ++j) { s0[j] = f2bfs(p[j]); s1[j] = f2bfs(p[8 + j]); }
      short* pd = pos_ct + (size_t)c * 32768 + tok0 + half * 16;
      *(short8*)pd = s0;
      *(short8*)(pd + 8) = s1;
    }
#pragma unroll
    for (int j = 0; j < 16; ++j) XQ[half * 16 + j][c] = f2bfs(a[j] + p[j]);
    ld16(k + gb, a); ld16(pk + gb, p);
#pragma unroll
    for (int j = 0; j < 16; ++j) XK[half * 16 + j][c] = f2bfs(a[j] + p[j]);
    ld16(v + gb, a);
#pragma unroll
    for (int j = 0; j < 16; ++j) XV[half * 16 + j][c] = f2bfs(a[j]);
  }
  __syncthreads();
  for (int i = 0; i < 3; ++i) {
    const int nt = wid + 4 * i;
    const int nch = nt * 32 + l31;
    const int which = nt >> 2;
    const short (*X)[132] = (which == 0) ? XQ : (which == 1) ? XK : XV;
    f32x16 acc = fzero16();
#pragma unroll
    for (int k0 = 0; k0 < 128; k0 += 16) {
      I4S8 af;
      af.h[0] = *(const int2*)&X[l31][k0 + 8 * g];
      af.h[1] = *(const int2*)&X[l31][k0 + 8 * g + 4];
      short8 bf = *(const short8*)(wbf + nch * CC + k0 + 8 * g);
      acc = __builtin_amdgcn_mfma_f32_32x32x16_bf16(af.s, bf, acc, 0, 0, 0);
    }
    const float bias = b_in[nch];
    const int hh = (nch >> 4) & 7, d = nch & 15;
    short* dst = (which == 0) ? qb : (which == 1) ? kb : vb;
    const float sc = (which == 0) ? QSC : 1.0f;
#pragma unroll
    for (int r = 0; r < 16; ++r) {
      const int tt = (r & 3) + 8 * (r >> 2) + 4 * g;
      dst[((size_t)((b0 + tt) * 8 + hh) * 64 + l) * 16 + d] =
          f2bfs((acc[r] + bias) * sc);
    }
  }
}

// ---------------- K2: unified MFMA flash attention ----------------
// Q64/wave + split-K2: wave (pair, qg, kh) handles 64 queries x SEQ/2 keys.
// Static-max exp2 makes k-half partials exactly additive (no rescale).
// acc[8] = ones-row lsum. kh=1 waves deposit partials in LDS; kh=0 combines.
template<int SEQ, int BATCH>
__global__ __launch_bounds__(256) void k_attn(
    const short* __restrict__ qsp, const short* __restrict__ ksp,
    const short* __restrict__ vsp, short* __restrict__ ao) {
  __shared__ short vt[4][17 * 36];
  __shared__ float comb[2][64][19];   // stride 19: conflict-free scatter
  const int tid = threadIdx.x;
  const int wid = tid >> 6, lane = tid & 63;
  const int l31 = lane & 31, g = lane >> 5;
  const int QG = SEQ / 64;
  // XCD-chunk swizzle (bijective for 2048 = 8*256 blocks)
  const int blk = ((blockIdx.x & 7) << 8) | (blockIdx.x >> 3);
  const int gw = blk * 4 + wid;
  const int kh = gw & 1;
  const int rest = gw >> 1;
  const int pair = rest / QG;
  const int q0 = (rest % QG) * 64;
  const int batch = pair >> 3, hh = pair & 7;
  const size_t pbase = (size_t)pair * (SEQ * 16);
  short* vtw = &vt[wid][0];
  // ones row (A rows 16..31): 18 lanes write one b32 each, once
  if (lane < 18) *(int*)(vtw + 16 * 36 + 2 * lane) = 0x3F803F80;

  const short8 qf0 = *(const short8*)(qsp + pbase + (size_t)(q0 + l31) * 16 + 8 * g);
  const short8 qf1 = *(const short8*)(qsp + pbase + (size_t)(q0 + 32 + l31) * 16 + 8 * g);

  f32x16 acc0 = fzero16(), acc1 = fzero16();
  const int arow = (l31 < 16) ? l31 : 16;
  const short* vtr = vtw + arow * 36;
  const int kbeg = kh * (SEQ / 2), kend = kbeg + SEQ / 2;

#pragma unroll 2
  for (int k0 = kbeg; k0 < kend; k0 += 32) {
    const short8 kf = *(const short8*)(ksp + pbase + (size_t)(k0 + l31) * 16 + 8 * g);
    const short8 vf = *(const short8*)(vsp + pbase + (size_t)(k0 + l31) * 16 + 8 * g);
#pragma unroll
    for (int j = 0; j < 8; ++j)
      vtw[(8 * g + j) * 36 + l31] = vf[j];

    f32x16 s0 = __builtin_amdgcn_mfma_f32_32x32x16_bf16(kf, qf0, fzero16(), 0, 0, 0);
    f32x16 s1 = __builtin_amdgcn_mfma_f32_32x32x16_bf16(kf, qf1, fzero16(), 0, 0, 0);

    I4S8 pa0, pb0, pa1, pb1;
#pragma unroll
    for (int j = 0; j < 4; ++j) {
      pa0.i[j] = (int)pk2(exp2_raw(s0[2 * j]), exp2_raw(s0[2 * j + 1]));
      pb0.i[j] = (int)pk2(exp2_raw(s0[8 + 2 * j]), exp2_raw(s0[9 + 2 * j]));
    }
#pragma unroll
    for (int j = 0; j < 4; ++j) {
      pa1.i[j] = (int)pk2(exp2_raw(s1[2 * j]), exp2_raw(s1[2 * j + 1]));
      pb1.i[j] = (int)pk2(exp2_raw(s1[8 + 2 * j]), exp2_raw(s1[9 + 2 * j]));
    }

    I4S8 a1, a2;
    a1.h[0] = *(const int2*)(vtr + 4 * g);
    a1.h[1] = *(const int2*)(vtr + 8 + 4 * g);
    a2.h[0] = *(const int2*)(vtr + 16 + 4 * g);
    a2.h[1] = *(const int2*)(vtr + 24 + 4 * g);
    acc0 = __builtin_amdgcn_mfma_f32_32x32x16_bf16(a1.s, pa0.s, acc0, 0, 0, 0);
    acc0 = __builtin_amdgcn_mfma_f32_32x32x16_bf16(a2.s, pb0.s, acc0, 0, 0, 0);
    acc1 = __builtin_amdgcn_mfma_f32_32x32x16_bf16(a1.s, pa1.s, acc1, 0, 0, 0);
    acc1 = __builtin_amdgcn_mfma_f32_32x32x16_bf16(a2.s, pb1.s, acc1, 0, 0, 0);
  }

  // ---- split-K combine: kh=1 deposits 18 partials/lane; kh=0 adds ----
  const int pi = wid >> 1;
  if (kh == 1) {
#pragma unroll
    for (int r = 0; r < 9; ++r) {
      comb[pi][lane][r] = acc0[r];
      comb[pi][lane][9 + r] = acc1[r];
    }
  }
  __syncthreads();
  if (kh == 1) return;
#pragma unroll
  for (int r = 0; r < 9; ++r) {
    acc0[r] += comb[pi][lane][r];
    acc1[r] += comb[pi][lane][9 + r];
  }

  const float inv0 = 1.0f / acc0[8];   // combined ones-row lsum
  const float inv1 = 1.0f / acc1[8];
  const int qi = q0 + l31;
  short* dst0 = ao + ((size_t)qi * BATCH + batch) * CC + hh * 16 + 4 * g;
  short* dst1 = ao + ((size_t)(qi + 32) * BATCH + batch) * CC + hh * 16 + 4 * g;
  uint2 o1, o2;
  o1.x = pk2(acc0[0] * inv0, acc0[1] * inv0);
  o1.y = pk2(acc0[2] * inv0, acc0[3] * inv0);
  o2.x = pk2(acc0[4] * inv0, acc0[5] * inv0);
  o2.y = pk2(acc0[6] * inv0, acc0[7] * inv0);
  *(uint2*)dst0 = o1;
  *(uint2*)(dst0 + 8) = o2;
  o1.x = pk2(acc1[0] * inv1, acc1[1] * inv1);
  o1.y = pk2(acc1[2] * inv1, acc1[3] * inv1);
  o2.x = pk2(acc1[4] * inv1, acc1[5] * inv1);
  o2.y = pk2(acc1[6] * inv1, acc1[7] * inv1);
  *(uint2*)dst1 = o1;
  *(uint2*)(dst1 + 8) = o2;
}

// ---------------- K3: long out-proj + pos + short QKV proj (MFMA x2) ----------------
__global__ __launch_bounds__(256) void k_mid(
    const short* __restrict__ ao, const short* __restrict__ pos_ct,
    const short* __restrict__ wobf, const float* __restrict__ b_out_l,
    const short* __restrict__ wibf, const float* __restrict__ b_in_s,
    short* __restrict__ qb, short* __restrict__ kb, short* __restrict__ vb) {
  __shared__ short YQK[32][132], YV[32][132];
  const int tid = threadIdx.x;
  const int wid = tid >> 6, lane = tid & 63;
  const int l31 = lane & 31, g = lane >> 5;
  const int tok0 = blockIdx.x * 32;
  const int l = tok0 >> 9, b0 = tok0 & 511;
  const int t = l >> 4, bh = (l >> 2) & 3, bw = l & 3;
  const int nb = b0 >> 8, ph0 = (b0 >> 4) & 15;
  {
    const int nch = wid * 32 + l31;
    f32x16 acc = fzero16();
#pragma unroll
    for (int k0 = 0; k0 < 128; k0 += 16) {
      short8 af = *(const short8*)(ao + (size_t)(tok0 + l31) * CC + k0 + 8 * g);
      short8 bf = *(const short8*)(wobf + nch * CC + k0 + 8 * g);
      acc = __builtin_amdgcn_mfma_f32_32x32x16_bf16(af, bf, acc, 0, 0, 0);
    }
    const float bias = b_out_l[nch];
    float pos[16];
#pragma unroll
    for (int rr = 0; rr < 4; ++rr) {
      int2 pp = *(const int2*)(pos_ct + (size_t)nch * 32768 + tok0 + rr * 8 + 4 * g);
      pos[rr * 4 + 0] = bflo((unsigned int)pp.x);
      pos[rr * 4 + 1] = bfhi((unsigned int)pp.x);
      pos[rr * 4 + 2] = bflo((unsigned int)pp.y);
      pos[rr * 4 + 3] = bfhi((unsigned int)pp.y);
    }
#pragma unroll
    for (int r = 0; r < 16; ++r) {
      const int tt = (r & 3) + 8 * (r >> 2) + 4 * g;
      const float y = acc[r] + bias;
      YV[tt][nch] = f2bfs(y);
      YQK[tt][nch] = f2bfs(y + pos[r]);
    }
  }
  __syncthreads();
  const int bs = nb * 16 + bh * 4 + bw;
  const int ls0 = (t * 16 + ph0) * 16;
  for (int i = 0; i < 3; ++i) {
    const int nt = wid + 4 * i;
    const int nch = nt * 32 + l31;
    const int which = nt >> 2;
    const short (*X)[132] = (which == 2) ? YV : YQK;
    f32x16 acc = fzero16();
#pragma unroll
    for (int k0 = 0; k0 < 128; k0 += 16) {
      I4S8 af;
      af.h[0] = *(const int2*)&X[l31][k0 + 8 * g];
      af.h[1] = *(const int2*)&X[l31][k0 + 8 * g + 4];
      short8 bf = *(const short8*)(wibf + nch * CC + k0 + 8 * g);
      acc = __builtin_amdgcn_mfma_f32_32x32x16_bf16(af.s, bf, acc, 0, 0, 0);
    }
    const float bias = b_in_s[nch];
    const int hh = (nch >> 4) & 7, d = nch & 15;
    short* dst = (which == 0) ? qb : (which == 1) ? kb : vb;
    const float sc = (which == 0) ? QSC : 1.0f;
    const size_t base = ((size_t)(bs * 8 + hh) * 1024 + ls0) * 16 + d;
#pragma unroll
    for (int r = 0; r < 16; ++r) {
      const int tt = (r & 3) + 8 * (r >> 2) + 4 * g;
      dst[base + (size_t)tt * 16] = f2bfs((acc[r] + bias) * sc);
    }
  }
}

// ---------------- K4: short out-proj + scatter to (N,C,T,H,W) fp32, MFMA ----------------
__global__ __launch_bounds__(256) void k_out_short(
    const short* __restrict__ ao, const short* __restrict__ wbf,
    const float* __restrict__ b_out, float* __restrict__ out) {
  const int tid = threadIdx.x;
  const int wid = tid >> 6, lane = tid & 63;
  const int l31 = lane & 31, g = lane >> 5;
  const int bs = blockIdx.x & 31;
  const int qi0 = (blockIdx.x >> 5) << 5;
  const int nb = bs >> 4, bh = (bs >> 2) & 3, bw = bs & 3;
  const int t = qi0 >> 8, ph0 = (qi0 >> 4) & 15;
  const int nch = wid * 32 + l31;
  f32x16 acc = fzero16();
#pragma unroll
  for (int k0 = 0; k0 < 128; k0 += 16) {
    short8 af = *(const short8*)(ao + ((size_t)(qi0 + l31) * 32 + bs) * CC + k0 + 8 * g);
    short8 bf = *(const short8*)(wbf + nch * CC + k0 + 8 * g);
    acc = __builtin_amdgcn_mfma_f32_32x32x16_bf16(af, bf, acc, 0, 0, 0);
  }
  const float bias = b_out[nch];
#pragma unroll
  for (int rr = 0; rr < 4; ++rr) {
    const int tt0 = rr * 8 + 4 * g;
    const int ph_off = tt0 >> 4, pw = tt0 & 15;
    const int h = bh * 16 + ph0 + ph_off, w = bw * 16 + pw;
    const size_t adr = (((size_t)(nb * CC + nch) * 4 + t) << 12) + h * 64 + w;
    float4 f;
    f.x = acc[rr * 4 + 0] + bias; f.y = acc[rr * 4 + 1] + bias;
    f.z = acc[rr * 4 + 2] + bias; f.w = acc[rr * 4 + 3] + bias;
    *(float4*)(out + adr) = f;
  }
}

extern "C" void kernel_launch(void* const* d_in, const int* in_sizes, int n_in,
                              void* d_out, int out_size, void* d_ws, size_t ws_size,
                              hipStream_t stream) {
  (void)in_sizes; (void)n_in; (void)out_size; (void)ws_size;
  const float* q   = (const float*)d_in[0];
  const float* k   = (const float*)d_in[1];
  const float* v   = (const float*)d_in[2];
  const float* pq  = (const float*)d_in[3];
  const float* pk  = (const float*)d_in[4];
  const float* wil = (const float*)d_in[5];
  const float* bil = (const float*)d_in[6];
  const float* wol = (const float*)d_in[7];
  const float* bol = (const float*)d_in[8];
  const float* wis = (const float*)d_in[9];
  const float* bis = (const float*)d_in[10];
  const float* wos = (const float*)d_in[11];
  const float* bos = (const float*)d_in[12];

  short* qs     = (short*)d_ws;            // 4.19M shorts each region
  short* ksb    = qs + 4194304;
  short* vsb    = ksb + 4194304;
  short* ao     = vsb + 4194304;
  short* pos_ct = ao + 4194304;
  short* wbf    = pos_ct + 4194304;        // 131072 shorts

  k_cvtw<<<dim3(64), dim3(256), 0, stream>>>(wil, wol, wis, wos, wbf);
  k_proj_long<<<dim3(1024), dim3(256), 0, stream>>>(q, k, v, pq, pk, wbf, bil,
                                                    qs, ksb, vsb, pos_ct);
  k_attn<64, 512><<<dim3(2048), dim3(256), 0, stream>>>(qs, ksb, vsb, ao);
  k_mid<<<dim3(1024), dim3(256), 0, stream>>>(ao, pos_ct, wbf + 49152, bol,
                                              wbf + 65536, bis, qs, ksb, vsb);
  k_attn<1024, 32><<<dim3(2048), dim3(256), 0, stream>>>(qs, ksb, vsb, ao);
  k_out_short<<<dim3(1024), dim3(256), 0, stream>>>(ao, wbf + 114688, bos,
                                                    (float*)d_out);
}